// Round 20
// baseline (88.862 us; speedup 1.0000x reference)
//
#include <hip/hip_runtime.h>
#include <hip/hip_bf16.h>
#include <cstdint>

#define B_ 8
#define S_ 2048
#define NI_ 1024
#define D_ 128
#define M_ (B_ * S_)  // 16384

typedef __attribute__((ext_vector_type(8))) short bf16x8;
typedef __attribute__((ext_vector_type(8))) unsigned short u16x8;
typedef __attribute__((ext_vector_type(4))) float f32x4;

__device__ __forceinline__ unsigned short f2bf(float f) {
    union { float f; uint32_t u; } v; v.f = f;
    uint32_t u = v.u;
    u += 0x7fff + ((u >> 16) & 1);  // RNE
    return (unsigned short)(u >> 16);
}

// async global->LDS, 16B per lane (dest = wave-uniform base + lane*16)
__device__ __forceinline__ void gload16(const void* g, void* l) {
    __builtin_amdgcn_global_load_lds((const __attribute__((address_space(1))) void*)g,
                                     (__attribute__((address_space(3))) void*)l, 16, 0, 0);
}

// ---------------- kernel 2: pack Wq/Wk/Wv ----------------
__global__ __launch_bounds__(256) void k_pack_w(const float* __restrict__ Wq, const float* __restrict__ bq,
                                                const float* __restrict__ Wk, const float* __restrict__ bk,
                                                const float* __restrict__ Wv, const float* __restrict__ bv,
                                                unsigned short* __restrict__ wb, float* __restrict__ bias) {
    int t = blockIdx.x * 256 + threadIdx.x;
    int e = t * 8;
    const float* src; int off;
    if (e < 131072)      { src = Wq; off = e; }
    else if (e < 262144) { src = Wk; off = e - 131072; }
    else                 { src = Wv; off = e - 262144; }
    float4 a = *(const float4*)(src + off);
    float4 b = *(const float4*)(src + off + 4);
    u16x8 r;
    r[0] = f2bf(a.x); r[1] = f2bf(a.y); r[2] = f2bf(a.z); r[3] = f2bf(a.w);
    r[4] = f2bf(b.x); r[5] = f2bf(b.y); r[6] = f2bf(b.z); r[7] = f2bf(b.w);
    *(u16x8*)(wb + e) = r;
    if (t < 384)
        bias[t] = (t < 128) ? bq[t] : (t < 256) ? bk[t - 128] : bv[t - 256];
}

// ---------------- kernel 3: QKV GEMM — R16/R19-passing kernel + XCD-aware block swizzle ----
// 768 blocks, 768%8==0 -> simple bijective swizzle (T1): XCD k executes a contiguous
// 96-work-item run (shared B panel + neighboring A rows -> L2-local reuse).
// Everything below the wi decomposition is byte-identical to the R19-passing kernel.
__global__ __launch_bounds__(256) void k_qkv(const float* __restrict__ x,
                                             const unsigned short* __restrict__ wb,
                                             const float* __restrict__ bias,
                                             unsigned short* __restrict__ q,
                                             unsigned short* __restrict__ kout,
                                             unsigned short* __restrict__ vT) {
    __shared__ __align__(16) unsigned short As[2][64 * 64];    // 2 x 8KB,  64 rows x 128B
    __shared__ __align__(16) unsigned short Bs[2][128 * 64];   // 2 x 16KB, 128 rows x 128B
    const int tid = threadIdx.x;
    const int flat = blockIdx.y * 256 + blockIdx.x;            // 0..767
    const int wi = (flat & 7) * 96 + (flat >> 3);              // bijective XCD swizzle
    const int m0 = (wi & 255) * 64;
    const int n0 = (wi >> 8) * 128;
    const int l = tid & 63, w = tid >> 6;
    const int wr = w >> 1, wc = w & 1;
    const int lr = l & 15, lg = l >> 4;
    const int lsw = (lr & 7) << 4;

    const int brow = tid >> 3;
    const int sB = ((tid & 7) * 8) ^ (((tid >> 3) & 7) << 3);

    const int arow = tid >> 2;
    const int acol = (tid & 3) * 16;
    const int amsk = (arow & 7) << 3;
    const int adst0 = arow * 64 + (acol ^ amsk);
    const int adst1 = arow * 64 + ((acol + 8) ^ amsk);

    f32x4 acc[2][4] = {};
    float4 a0, a1, a2, a3;

#define LOADA(k0off) do { \
    const float* xg = x + (long)(m0 + arow) * NI_ + (k0off) + acol; \
    a0 = *(const float4*)xg;        a1 = *(const float4*)(xg + 4); \
    a2 = *(const float4*)(xg + 8);  a3 = *(const float4*)(xg + 12); } while (0)

#define GLOADB(buf, k0off) do { \
    _Pragma("unroll") \
    for (int c = 0; c < 4; c++) \
        gload16(wb + (long)(n0 + c * 32 + brow) * NI_ + (k0off) + sB, \
                (unsigned short*)Bs[buf] + c * 2048 + tid * 8); } while (0)

#define CVTWRITEA(buf) do { \
    union { __hip_bfloat162 h[4]; u16x8 v; } r0, r1; \
    r0.h[0] = __float22bfloat162_rn(make_float2(a0.x, a0.y)); \
    r0.h[1] = __float22bfloat162_rn(make_float2(a0.z, a0.w)); \
    r0.h[2] = __float22bfloat162_rn(make_float2(a1.x, a1.y)); \
    r0.h[3] = __float22bfloat162_rn(make_float2(a1.z, a1.w)); \
    r1.h[0] = __float22bfloat162_rn(make_float2(a2.x, a2.y)); \
    r1.h[1] = __float22bfloat162_rn(make_float2(a2.z, a2.w)); \
    r1.h[2] = __float22bfloat162_rn(make_float2(a3.x, a3.y)); \
    r1.h[3] = __float22bfloat162_rn(make_float2(a3.z, a3.w)); \
    *(u16x8*)((unsigned short*)As[buf] + adst0) = r0.v; \
    *(u16x8*)((unsigned short*)As[buf] + adst1) = r1.v; } while (0)

    LOADA(0);
    GLOADB(0, 0);
    CVTWRITEA(0);
    __syncthreads();

    int cur = 0;
    for (int k0 = 0; k0 < NI_; k0 += 64) {
        bool more = (k0 + 64 < NI_);
        if (more) {
            GLOADB(cur ^ 1, k0 + 64);
            LOADA(k0 + 64);
        }

        const char* ad = (const char*)As[cur];
        const char* bd = (const char*)Bs[cur];
        bf16x8 a[2][2], b[4][2];
#pragma unroll
        for (int i = 0; i < 2; i++)
#pragma unroll
            for (int kc = 0; kc < 2; kc++)
                a[i][kc] = *(const bf16x8*)(ad + (wr * 32 + i * 16 + lr) * 128
                                               + ((kc * 64 + lg * 16) ^ lsw));
#pragma unroll
        for (int j = 0; j < 4; j++)
#pragma unroll
            for (int kc = 0; kc < 2; kc++)
                b[j][kc] = *(const bf16x8*)(bd + (wc * 64 + j * 16 + lr) * 128
                                               + ((kc * 64 + lg * 16) ^ lsw));
#pragma unroll
        for (int kc = 0; kc < 2; kc++)
#pragma unroll
            for (int i = 0; i < 2; i++)
#pragma unroll
                for (int j = 0; j < 4; j++)
                    acc[i][j] = __builtin_amdgcn_mfma_f32_16x16x32_bf16(a[i][kc], b[j][kc], acc[i][j], 0, 0, 0);

        if (more) CVTWRITEA(cur ^ 1);
        __syncthreads();
        cur ^= 1;
    }
#undef LOADA
#undef GLOADB
#undef CVTWRITEA

#pragma unroll
    for (int i = 0; i < 2; i++)
#pragma unroll
        for (int j = 0; j < 4; j++)
#pragma unroll
            for (int r = 0; r < 4; r++) {
                int row = m0 + wr * 32 + i * 16 + lg * 4 + r;
                int n = n0 + wc * 64 + j * 16 + lr;
                float val = acc[i][j][r] + bias[n];
                unsigned short bv16 = f2bf(val);
                if (n0 == 0)        q[(long)row * 128 + n] = bv16;
                else if (n0 == 128) kout[(long)row * 128 + (n - 128)] = bv16;
                else {
                    int bb = row >> 11, s = row & 2047, d = n - 256;
                    vT[((long)bb * 128 + d) * (long)S_ + s] = bv16;
                }
            }
}

// ---------------- kernel 4: attention — byte-identical to the R16/R19-passing kernel ------
#define SHIFT_ 16.0f
__global__ __launch_bounds__(256, 2) void k_attn(const unsigned short* __restrict__ q,
                                                 const unsigned short* __restrict__ kk,
                                                 const unsigned short* __restrict__ vT,
                                                 float* __restrict__ o_part,
                                                 float* __restrict__ L_part) {
    __shared__ __align__(16) unsigned short Kl[2 * 64 * 128];   // 32KB dbuf, swizzled
    __shared__ __align__(16) unsigned short Vl[2 * 128 * 64];   // 32KB dbuf, swizzled
    __shared__ __align__(16) unsigned short Plds[4 * 32 * 64];  // 16KB, wave-private
    const int tid = threadIdx.x, l = tid & 63, w = tid >> 6;
    const int b = blockIdx.z, ks = blockIdx.y;
    const int q0 = blockIdx.x * 128 + w * 32;
    const int lr = l & 15, lg = l >> 4;
    const unsigned short* qB = q  + (long)b * S_ * 128;
    const unsigned short* kB = kk + (long)b * S_ * 128;
    const unsigned short* vB = vT + (long)b * 128 * S_;
    char* Pw = (char*)Plds + w * 4096;
    const int kv_base = ks * 512;
    const int lsw = (lr & 7) << 4;

    const int krowc = tid >> 4;
    const int ksrc  = ((tid & 15) * 8) ^ (((tid >> 4) & 7) << 3);
    const int vrowc = tid >> 3;
    const int vsrc  = ((tid & 7) * 8) ^ (((tid >> 3) & 7) << 3);

#define STAGEKV(buf, kvoff) do { \
    unsigned short* kdst = (unsigned short*)Kl + (buf) * 8192; \
    unsigned short* vdst = (unsigned short*)Vl + (buf) * 8192; \
    _Pragma("unroll") \
    for (int c = 0; c < 4; c++) { \
        gload16(kB + (long)((kvoff) + c * 16 + krowc) * 128 + ksrc, kdst + c * 2048 + tid * 8); \
        gload16(vB + (long)(c * 32 + vrowc) * S_ + (kvoff) + vsrc,  vdst + c * 2048 + tid * 8); \
    } } while (0)

    bf16x8 qf[2][4];
#pragma unroll
    for (int a = 0; a < 2; a++)
#pragma unroll
        for (int kc = 0; kc < 4; kc++)
            qf[a][kc] = *(const bf16x8*)(qB + (long)(q0 + a * 16 + lr) * 128 + kc * 32 + lg * 8);

    STAGEKV(0, kv_base);
    __syncthreads();

    float psum[2][4] = {};
    f32x4 o[2][8] = {};
    int cur = 0;

    for (int t = 0; t < 8; t++) {
        if (t < 7) STAGEKV(cur ^ 1, kv_base + (t + 1) * 64);

        const char* kd = (const char*)Kl + cur * 16384;
        const char* vd = (const char*)Vl + cur * 16384;

        f32x4 sa[2][4] = {};
#pragma unroll
        for (int j = 0; j < 4; j++) {
            bf16x8 kf[4];
#pragma unroll
            for (int kc = 0; kc < 4; kc++)
                kf[kc] = *(const bf16x8*)(kd + (((j * 16 + lr) * 256 + kc * 64 + lg * 16) ^ lsw));
#pragma unroll
            for (int a = 0; a < 2; a++)
#pragma unroll
                for (int kc = 0; kc < 4; kc++)
                    sa[a][j] = __builtin_amdgcn_mfma_f32_16x16x32_bf16(qf[a][kc], kf[kc], sa[a][j], 0, 0, 0);
        }

#pragma unroll
        for (int a = 0; a < 2; a++)
#pragma unroll
            for (int r = 0; r < 4; r++) {
                int row = a * 16 + lg * 4 + r;
#pragma unroll
                for (int j = 0; j < 4; j++) {
                    float pj = __expf(sa[a][j][r] - SHIFT_);
                    psum[a][r] += pj;
                    int bo = (row * 128 + (j * 16 + lr) * 2) ^ ((row & 7) << 4);
                    *(unsigned short*)(Pw + bo) = f2bf(pj);
                }
            }

        bf16x8 pa[2][2];
#pragma unroll
        for (int a = 0; a < 2; a++) {
            pa[a][0] = *(const bf16x8*)(Pw + (((a * 16 + lr) * 128 + lg * 16) ^ lsw));
            pa[a][1] = *(const bf16x8*)(Pw + (((a * 16 + lr) * 128 + 64 + lg * 16) ^ lsw));
        }

#pragma unroll
        for (int c = 0; c < 8; c++) {
            int dr = c * 16 + lr;
            bf16x8 vf0 = *(const bf16x8*)(vd + ((dr * 128 + lg * 16) ^ lsw));
            bf16x8 vf1 = *(const bf16x8*)(vd + ((dr * 128 + 64 + lg * 16) ^ lsw));
#pragma unroll
            for (int a = 0; a < 2; a++) {
                o[a][c] = __builtin_amdgcn_mfma_f32_16x16x32_bf16(pa[a][0], vf0, o[a][c], 0, 0, 0);
                o[a][c] = __builtin_amdgcn_mfma_f32_16x16x32_bf16(pa[a][1], vf1, o[a][c], 0, 0, 0);
            }
        }

        __syncthreads();
        cur ^= 1;
    }
#undef STAGEKV

#pragma unroll
    for (int a = 0; a < 2; a++)
#pragma unroll
        for (int r = 0; r < 4; r++) {
            float ps = psum[a][r];
            ps += __shfl_xor(ps, 1);
            ps += __shfl_xor(ps, 2);
            ps += __shfl_xor(ps, 4);
            ps += __shfl_xor(ps, 8);
            if (lr == 0)
                L_part[((long)ks * B_ + b) * S_ + q0 + a * 16 + lg * 4 + r] = ps;
        }
#pragma unroll
    for (int a = 0; a < 2; a++)
#pragma unroll
        for (int c = 0; c < 8; c++)
#pragma unroll
            for (int r = 0; r < 4; r++) {
                int row = q0 + a * 16 + lg * 4 + r, col = c * 16 + lr;
                o_part[(((long)ks * B_ + b) * S_ + row) * 128 + col] = o[a][c][r];
            }
}

// ---------------- kernel 5: combine 4 KV-split partials ----------------
__global__ __launch_bounds__(256) void k_comb(const float* __restrict__ op,
                                              const float* __restrict__ Lp,
                                              float* __restrict__ out) {
    int t = blockIdx.x * 256 + threadIdx.x;  // 524,288 threads
    int row = t >> 5;
    int c4 = (t & 31) * 4;
    float ax = 0.f, ay = 0.f, az = 0.f, aw = 0.f, Ls = 0.f;
#pragma unroll
    for (int ts = 0; ts < 4; ts++) {
        float4 v = *(const float4*)(op + (((long)ts * M_ + row) << 7) + c4);
        ax += v.x; ay += v.y; az += v.z; aw += v.w;
        Ls += Lp[(long)ts * M_ + row];
    }
    float inv = 1.f / Ls;
    float4 r; r.x = ax * inv; r.y = ay * inv; r.z = az * inv; r.w = aw * inv;
    *(float4*)(out + ((long)row << 7) + c4) = r;
}

extern "C" void kernel_launch(void* const* d_in, const int* in_sizes, int n_in,
                              void* d_out, int out_size, void* d_ws, size_t ws_size,
                              hipStream_t stream) {
    const float* x  = (const float*)d_in[0];
    const float* Wq = (const float*)d_in[1];
    const float* bq = (const float*)d_in[2];
    const float* Wk = (const float*)d_in[3];
    const float* bk = (const float*)d_in[4];
    const float* Wv = (const float*)d_in[5];
    const float* bv = (const float*)d_in[6];
    float* out = (float*)d_out;

    char* ws = (char*)d_ws;
    unsigned short* wb   = (unsigned short*)(ws + 33554432);
    float*          bias = (float*)(ws + 33554432 + 786432);
    unsigned short* qb   = (unsigned short*)(ws + 34344960);
    unsigned short* kb   = (unsigned short*)(ws + 38539264);
    unsigned short* vT   = (unsigned short*)(ws + 42733568);      // ends 46,927,872
    float* o_part = (float*)(ws);                                 // 33.5MB
    float* L_part = (float*)(ws + 46927872);

    k_pack_w<<<192, 256, 0, stream>>>(Wq, bq, Wk, bk, Wv, bv, wb, bias);
    k_qkv<<<dim3(256, 3), 256, 0, stream>>>(x, wb, bias, qb, kb, vT);
    k_attn<<<dim3(16, 4, 8), 256, 0, stream>>>(qb, kb, vT, o_part, L_part);
    k_comb<<<2048, 256, 0, stream>>>(o_part, L_part, out);
}

// Round 21
// 77.849 us; speedup vs baseline: 1.1415x; 1.1415x over previous
//
#include <hip/hip_runtime.h>
#include <hip/hip_bf16.h>
#include <cstdint>

#define B_ 8
#define S_ 2048
#define NI_ 1024
#define D_ 128
#define M_ (B_ * S_)  // 16384

typedef __attribute__((ext_vector_type(8))) short bf16x8;
typedef __attribute__((ext_vector_type(8))) unsigned short u16x8;
typedef __attribute__((ext_vector_type(4))) float f32x4;

__device__ __forceinline__ unsigned short f2bf(float f) {
    union { float f; uint32_t u; } v; v.f = f;
    uint32_t u = v.u;
    u += 0x7fff + ((u >> 16) & 1);  // RNE
    return (unsigned short)(u >> 16);
}

// async global->LDS, 16B per lane (dest = wave-uniform base + lane*16)
__device__ __forceinline__ void gload16(const void* g, void* l) {
    __builtin_amdgcn_global_load_lds((const __attribute__((address_space(1))) void*)g,
                                     (__attribute__((address_space(3))) void*)l, 16, 0, 0);
}

// ---------------- kernel 2: pack Wq/Wk/Wv ----------------
__global__ __launch_bounds__(256) void k_pack_w(const float* __restrict__ Wq, const float* __restrict__ bq,
                                                const float* __restrict__ Wk, const float* __restrict__ bk,
                                                const float* __restrict__ Wv, const float* __restrict__ bv,
                                                unsigned short* __restrict__ wb, float* __restrict__ bias) {
    int t = blockIdx.x * 256 + threadIdx.x;
    int e = t * 8;
    const float* src; int off;
    if (e < 131072)      { src = Wq; off = e; }
    else if (e < 262144) { src = Wk; off = e - 131072; }
    else                 { src = Wv; off = e - 262144; }
    float4 a = *(const float4*)(src + off);
    float4 b = *(const float4*)(src + off + 4);
    u16x8 r;
    r[0] = f2bf(a.x); r[1] = f2bf(a.y); r[2] = f2bf(a.z); r[3] = f2bf(a.w);
    r[4] = f2bf(b.x); r[5] = f2bf(b.y); r[6] = f2bf(b.z); r[7] = f2bf(b.w);
    *(u16x8*)(wb + e) = r;
    if (t < 384)
        bias[t] = (t < 128) ? bq[t] : (t < 256) ? bk[t - 128] : bv[t - 256];
}

// ---------------- kernel 3: QKV GEMM — R16/R19-measured kernel (77.9µs config) ----------
// 64x128 tile, BK=64, dbuf, XOR-swizzled LDS, A reg-staged fused f32->bf16 (coalesced),
// B gload16 with pre-swizzled source. Grid (256,3)=768 blocks, default dispatch order
// (R20 showed default order already captures A-row reuse; XCD remap destroyed it).
__global__ __launch_bounds__(256) void k_qkv(const float* __restrict__ x,
                                             const unsigned short* __restrict__ wb,
                                             const float* __restrict__ bias,
                                             unsigned short* __restrict__ q,
                                             unsigned short* __restrict__ kout,
                                             unsigned short* __restrict__ vT) {
    __shared__ __align__(16) unsigned short As[2][64 * 64];    // 2 x 8KB,  64 rows x 128B
    __shared__ __align__(16) unsigned short Bs[2][128 * 64];   // 2 x 16KB, 128 rows x 128B
    const int tid = threadIdx.x;
    const int m0 = blockIdx.x * 64;
    const int n0 = blockIdx.y * 128;
    const int l = tid & 63, w = tid >> 6;
    const int wr = w >> 1, wc = w & 1;
    const int lr = l & 15, lg = l >> 4;
    const int lsw = (lr & 7) << 4;

    const int brow = tid >> 3;
    const int sB = ((tid & 7) * 8) ^ (((tid >> 3) & 7) << 3);

    const int arow = tid >> 2;
    const int acol = (tid & 3) * 16;
    const int amsk = (arow & 7) << 3;
    const int adst0 = arow * 64 + (acol ^ amsk);
    const int adst1 = arow * 64 + ((acol + 8) ^ amsk);

    f32x4 acc[2][4] = {};
    float4 a0, a1, a2, a3;

#define LOADA(k0off) do { \
    const float* xg = x + (long)(m0 + arow) * NI_ + (k0off) + acol; \
    a0 = *(const float4*)xg;        a1 = *(const float4*)(xg + 4); \
    a2 = *(const float4*)(xg + 8);  a3 = *(const float4*)(xg + 12); } while (0)

#define GLOADB(buf, k0off) do { \
    _Pragma("unroll") \
    for (int c = 0; c < 4; c++) \
        gload16(wb + (long)(n0 + c * 32 + brow) * NI_ + (k0off) + sB, \
                (unsigned short*)Bs[buf] + c * 2048 + tid * 8); } while (0)

#define CVTWRITEA(buf) do { \
    union { __hip_bfloat162 h[4]; u16x8 v; } r0, r1; \
    r0.h[0] = __float22bfloat162_rn(make_float2(a0.x, a0.y)); \
    r0.h[1] = __float22bfloat162_rn(make_float2(a0.z, a0.w)); \
    r0.h[2] = __float22bfloat162_rn(make_float2(a1.x, a1.y)); \
    r0.h[3] = __float22bfloat162_rn(make_float2(a1.z, a1.w)); \
    r1.h[0] = __float22bfloat162_rn(make_float2(a2.x, a2.y)); \
    r1.h[1] = __float22bfloat162_rn(make_float2(a2.z, a2.w)); \
    r1.h[2] = __float22bfloat162_rn(make_float2(a3.x, a3.y)); \
    r1.h[3] = __float22bfloat162_rn(make_float2(a3.z, a3.w)); \
    *(u16x8*)((unsigned short*)As[buf] + adst0) = r0.v; \
    *(u16x8*)((unsigned short*)As[buf] + adst1) = r1.v; } while (0)

    LOADA(0);
    GLOADB(0, 0);
    CVTWRITEA(0);
    __syncthreads();

    int cur = 0;
    for (int k0 = 0; k0 < NI_; k0 += 64) {
        bool more = (k0 + 64 < NI_);
        if (more) {
            GLOADB(cur ^ 1, k0 + 64);
            LOADA(k0 + 64);
        }

        const char* ad = (const char*)As[cur];
        const char* bd = (const char*)Bs[cur];
        bf16x8 a[2][2], b[4][2];
#pragma unroll
        for (int i = 0; i < 2; i++)
#pragma unroll
            for (int kc = 0; kc < 2; kc++)
                a[i][kc] = *(const bf16x8*)(ad + (wr * 32 + i * 16 + lr) * 128
                                               + ((kc * 64 + lg * 16) ^ lsw));
#pragma unroll
        for (int j = 0; j < 4; j++)
#pragma unroll
            for (int kc = 0; kc < 2; kc++)
                b[j][kc] = *(const bf16x8*)(bd + (wc * 64 + j * 16 + lr) * 128
                                               + ((kc * 64 + lg * 16) ^ lsw));
#pragma unroll
        for (int kc = 0; kc < 2; kc++)
#pragma unroll
            for (int i = 0; i < 2; i++)
#pragma unroll
                for (int j = 0; j < 4; j++)
                    acc[i][j] = __builtin_amdgcn_mfma_f32_16x16x32_bf16(a[i][kc], b[j][kc], acc[i][j], 0, 0, 0);

        if (more) CVTWRITEA(cur ^ 1);
        __syncthreads();
        cur ^= 1;
    }
#undef LOADA
#undef GLOADB
#undef CVTWRITEA

#pragma unroll
    for (int i = 0; i < 2; i++)
#pragma unroll
        for (int j = 0; j < 4; j++)
#pragma unroll
            for (int r = 0; r < 4; r++) {
                int row = m0 + wr * 32 + i * 16 + lg * 4 + r;
                int n = n0 + wc * 64 + j * 16 + lr;
                float val = acc[i][j][r] + bias[n];
                unsigned short bv16 = f2bf(val);
                if (n0 == 0)        q[(long)row * 128 + n] = bv16;
                else if (n0 == 128) kout[(long)row * 128 + (n - 128)] = bv16;
                else {
                    int bb = row >> 11, s = row & 2047, d = n - 256;
                    vT[((long)bb * 128 + d) * (long)S_ + s] = bv16;
                }
            }
}

// ---------------- kernel 4: attention — R16/R19-measured kernel (gload16 K/V staging) -----
#define SHIFT_ 16.0f
__global__ __launch_bounds__(256, 2) void k_attn(const unsigned short* __restrict__ q,
                                                 const unsigned short* __restrict__ kk,
                                                 const unsigned short* __restrict__ vT,
                                                 float* __restrict__ o_part,
                                                 float* __restrict__ L_part) {
    __shared__ __align__(16) unsigned short Kl[2 * 64 * 128];   // 32KB dbuf, swizzled
    __shared__ __align__(16) unsigned short Vl[2 * 128 * 64];   // 32KB dbuf, swizzled
    __shared__ __align__(16) unsigned short Plds[4 * 32 * 64];  // 16KB, wave-private
    const int tid = threadIdx.x, l = tid & 63, w = tid >> 6;
    const int b = blockIdx.z, ks = blockIdx.y;
    const int q0 = blockIdx.x * 128 + w * 32;
    const int lr = l & 15, lg = l >> 4;
    const unsigned short* qB = q  + (long)b * S_ * 128;
    const unsigned short* kB = kk + (long)b * S_ * 128;
    const unsigned short* vB = vT + (long)b * 128 * S_;
    char* Pw = (char*)Plds + w * 4096;
    const int kv_base = ks * 512;
    const int lsw = (lr & 7) << 4;

    const int krowc = tid >> 4;
    const int ksrc  = ((tid & 15) * 8) ^ (((tid >> 4) & 7) << 3);
    const int vrowc = tid >> 3;
    const int vsrc  = ((tid & 7) * 8) ^ (((tid >> 3) & 7) << 3);

#define STAGEKV(buf, kvoff) do { \
    unsigned short* kdst = (unsigned short*)Kl + (buf) * 8192; \
    unsigned short* vdst = (unsigned short*)Vl + (buf) * 8192; \
    _Pragma("unroll") \
    for (int c = 0; c < 4; c++) { \
        gload16(kB + (long)((kvoff) + c * 16 + krowc) * 128 + ksrc, kdst + c * 2048 + tid * 8); \
        gload16(vB + (long)(c * 32 + vrowc) * S_ + (kvoff) + vsrc,  vdst + c * 2048 + tid * 8); \
    } } while (0)

    bf16x8 qf[2][4];
#pragma unroll
    for (int a = 0; a < 2; a++)
#pragma unroll
        for (int kc = 0; kc < 4; kc++)
            qf[a][kc] = *(const bf16x8*)(qB + (long)(q0 + a * 16 + lr) * 128 + kc * 32 + lg * 8);

    STAGEKV(0, kv_base);
    __syncthreads();

    float psum[2][4] = {};
    f32x4 o[2][8] = {};
    int cur = 0;

    for (int t = 0; t < 8; t++) {
        if (t < 7) STAGEKV(cur ^ 1, kv_base + (t + 1) * 64);

        const char* kd = (const char*)Kl + cur * 16384;
        const char* vd = (const char*)Vl + cur * 16384;

        f32x4 sa[2][4] = {};
#pragma unroll
        for (int j = 0; j < 4; j++) {
            bf16x8 kf[4];
#pragma unroll
            for (int kc = 0; kc < 4; kc++)
                kf[kc] = *(const bf16x8*)(kd + (((j * 16 + lr) * 256 + kc * 64 + lg * 16) ^ lsw));
#pragma unroll
            for (int a = 0; a < 2; a++)
#pragma unroll
                for (int kc = 0; kc < 4; kc++)
                    sa[a][j] = __builtin_amdgcn_mfma_f32_16x16x32_bf16(qf[a][kc], kf[kc], sa[a][j], 0, 0, 0);
        }

#pragma unroll
        for (int a = 0; a < 2; a++)
#pragma unroll
            for (int r = 0; r < 4; r++) {
                int row = a * 16 + lg * 4 + r;
#pragma unroll
                for (int j = 0; j < 4; j++) {
                    float pj = __expf(sa[a][j][r] - SHIFT_);
                    psum[a][r] += pj;
                    int bo = (row * 128 + (j * 16 + lr) * 2) ^ ((row & 7) << 4);
                    *(unsigned short*)(Pw + bo) = f2bf(pj);
                }
            }

        bf16x8 pa[2][2];
#pragma unroll
        for (int a = 0; a < 2; a++) {
            pa[a][0] = *(const bf16x8*)(Pw + (((a * 16 + lr) * 128 + lg * 16) ^ lsw));
            pa[a][1] = *(const bf16x8*)(Pw + (((a * 16 + lr) * 128 + 64 + lg * 16) ^ lsw));
        }

#pragma unroll
        for (int c = 0; c < 8; c++) {
            int dr = c * 16 + lr;
            bf16x8 vf0 = *(const bf16x8*)(vd + ((dr * 128 + lg * 16) ^ lsw));
            bf16x8 vf1 = *(const bf16x8*)(vd + ((dr * 128 + 64 + lg * 16) ^ lsw));
#pragma unroll
            for (int a = 0; a < 2; a++) {
                o[a][c] = __builtin_amdgcn_mfma_f32_16x16x32_bf16(pa[a][0], vf0, o[a][c], 0, 0, 0);
                o[a][c] = __builtin_amdgcn_mfma_f32_16x16x32_bf16(pa[a][1], vf1, o[a][c], 0, 0, 0);
            }
        }

        __syncthreads();
        cur ^= 1;
    }
#undef STAGEKV

#pragma unroll
    for (int a = 0; a < 2; a++)
#pragma unroll
        for (int r = 0; r < 4; r++) {
            float ps = psum[a][r];
            ps += __shfl_xor(ps, 1);
            ps += __shfl_xor(ps, 2);
            ps += __shfl_xor(ps, 4);
            ps += __shfl_xor(ps, 8);
            if (lr == 0)
                L_part[((long)ks * B_ + b) * S_ + q0 + a * 16 + lg * 4 + r] = ps;
        }
#pragma unroll
    for (int a = 0; a < 2; a++)
#pragma unroll
        for (int c = 0; c < 8; c++)
#pragma unroll
            for (int r = 0; r < 4; r++) {
                int row = q0 + a * 16 + lg * 4 + r, col = c * 16 + lr;
                o_part[(((long)ks * B_ + b) * S_ + row) * 128 + col] = o[a][c][r];
            }
}

// ---------------- kernel 5: combine 4 KV-split partials ----------------
__global__ __launch_bounds__(256) void k_comb(const float* __restrict__ op,
                                              const float* __restrict__ Lp,
                                              float* __restrict__ out) {
    int t = blockIdx.x * 256 + threadIdx.x;  // 524,288 threads
    int row = t >> 5;
    int c4 = (t & 31) * 4;
    float ax = 0.f, ay = 0.f, az = 0.f, aw = 0.f, Ls = 0.f;
#pragma unroll
    for (int ts = 0; ts < 4; ts++) {
        float4 v = *(const float4*)(op + (((long)ts * M_ + row) << 7) + c4);
        ax += v.x; ay += v.y; az += v.z; aw += v.w;
        Ls += Lp[(long)ts * M_ + row];
    }
    float inv = 1.f / Ls;
    float4 r; r.x = ax * inv; r.y = ay * inv; r.z = az * inv; r.w = aw * inv;
    *(float4*)(out + ((long)row << 7) + c4) = r;
}

extern "C" void kernel_launch(void* const* d_in, const int* in_sizes, int n_in,
                              void* d_out, int out_size, void* d_ws, size_t ws_size,
                              hipStream_t stream) {
    const float* x  = (const float*)d_in[0];
    const float* Wq = (const float*)d_in[1];
    const float* bq = (const float*)d_in[2];
    const float* Wk = (const float*)d_in[3];
    const float* bk = (const float*)d_in[4];
    const float* Wv = (const float*)d_in[5];
    const float* bv = (const float*)d_in[6];
    float* out = (float*)d_out;

    char* ws = (char*)d_ws;
    unsigned short* wb   = (unsigned short*)(ws + 33554432);
    float*          bias = (float*)(ws + 33554432 + 786432);
    unsigned short* qb   = (unsigned short*)(ws + 34344960);
    unsigned short* kb   = (unsigned short*)(ws + 38539264);
    unsigned short* vT   = (unsigned short*)(ws + 42733568);      // ends 46,927,872
    float* o_part = (float*)(ws);                                 // 33.5MB
    float* L_part = (float*)(ws + 46927872);

    k_pack_w<<<192, 256, 0, stream>>>(Wq, bq, Wk, bk, Wv, bv, wb, bias);
    k_qkv<<<dim3(256, 3), 256, 0, stream>>>(x, wb, bias, qb, kb, vT);
    k_attn<<<dim3(16, 4, 8), 256, 0, stream>>>(qb, kb, vT, o_part, L_part);
    k_comb<<<2048, 256, 0, stream>>>(o_part, L_part, out);
}